// Round 3
// baseline (572.009 us; speedup 1.0000x reference)
//
#include <hip/hip_runtime.h>
#include <math.h>

#define NEG_SLOPE 0.2f

static __device__ __forceinline__ float leaky(float x) {
  return x > 0.0f ? x : NEG_SLOPE * x;
}

// ---------------- CSR build ----------------
__global__ void zero_kernel(int* __restrict__ p, int n) {
  int i = blockIdx.x * blockDim.x + threadIdx.x;
  if (i < n) p[i] = 0;
}

__global__ void count_kernel(const int* __restrict__ ei, int* __restrict__ counts, int E) {
  int i = blockIdx.x * blockDim.x + threadIdx.x;
  if (i < E) atomicAdd(&counts[ei[E + i]], 1);
}

// single block, 1024 threads: exclusive scan of counts -> offs, cursor
__global__ void scan_kernel(const int* __restrict__ counts, int* __restrict__ offs,
                            int* __restrict__ cursor, int N) {
  __shared__ int sums[1024];
  int tid = threadIdx.x;
  int chunk = (N + 1023) >> 10;
  int start = tid * chunk;
  int end = min(start + chunk, N);
  int s = 0;
  for (int i = start; i < end; ++i) s += counts[i];
  sums[tid] = s;
  __syncthreads();
  for (int off = 1; off < 1024; off <<= 1) {
    int v = (tid >= off) ? sums[tid - off] : 0;
    __syncthreads();
    sums[tid] += v;
    __syncthreads();
  }
  int run = (tid > 0) ? sums[tid - 1] : 0;
  for (int i = start; i < end; ++i) {
    offs[i] = run;
    cursor[i] = run;
    run += counts[i];
  }
  if (tid == 0) offs[N] = sums[1023];
}

__global__ void fill_kernel(const int* __restrict__ ei, int* __restrict__ cursor,
                            int* __restrict__ csr, int E) {
  int i = blockIdx.x * blockDim.x + threadIdx.x;
  if (i < E) {
    int src = ei[i];
    int dst = ei[E + i];
    int pos = atomicAdd(&cursor[dst], 1);
    csr[pos] = src;
  }
}

// ---------------- generic tiled f32 GEMM: C[M,N] = A[M,K] @ B[K,N] (+bias) ----------------
// 64x64 tile, TK=16, 256 threads, 4x4 micro-tile. K must be a multiple of 16.
template <bool BIAS>
__global__ __launch_bounds__(256) void gemm_tiled(const float* __restrict__ A,
                                                  const float* __restrict__ B,
                                                  const float* __restrict__ bias,
                                                  float* __restrict__ C,
                                                  int M, int N, int K) {
  __shared__ float As[16][68];  // transposed: As[k][m]
  __shared__ float Bs[16][68];
  int tid = threadIdx.x;
  int tx = tid & 15, ty = tid >> 4;
  int brow = blockIdx.x * 64, bcol = blockIdx.y * 64;

  float acc[4][4] = {};

  int arow = tid >> 2;         // 0..63
  int akv = (tid & 3) * 4;     // 0,4,8,12
  int bkk = tid >> 4;          // 0..15
  int bcv = (tid & 15) * 4;    // 0..60

  for (int k0 = 0; k0 < K; k0 += 16) {
    int gr = min(brow + arow, M - 1);
    float4 av = *(const float4*)&A[(size_t)gr * K + k0 + akv];
    float4 bv;
    int gc = bcol + bcv;
    if (gc + 3 < N)
      bv = *(const float4*)&B[(size_t)(k0 + bkk) * N + gc];
    else
      bv = make_float4(0.f, 0.f, 0.f, 0.f);

    __syncthreads();
    As[akv + 0][arow] = av.x;
    As[akv + 1][arow] = av.y;
    As[akv + 2][arow] = av.z;
    As[akv + 3][arow] = av.w;
    *(float4*)&Bs[bkk][bcv] = bv;
    __syncthreads();

#pragma unroll
    for (int kk = 0; kk < 16; ++kk) {
      float4 a4 = *(const float4*)&As[kk][ty * 4];
      float4 b4 = *(const float4*)&Bs[kk][tx * 4];
      float ar[4] = {a4.x, a4.y, a4.z, a4.w};
      float br[4] = {b4.x, b4.y, b4.z, b4.w};
#pragma unroll
      for (int i = 0; i < 4; ++i)
#pragma unroll
        for (int j = 0; j < 4; ++j) acc[i][j] = fmaf(ar[i], br[j], acc[i][j]);
    }
  }

#pragma unroll
  for (int i = 0; i < 4; ++i) {
    int r = brow + ty * 4 + i;
    if (r >= M) continue;
#pragma unroll
    for (int j = 0; j < 4; ++j) {
      int c = bcol + tx * 4 + j;
      if (c >= N) continue;
      float v = acc[i][j];
      if (BIAS) v += bias[c];
      C[(size_t)r * N + c] = v;
    }
  }
}

// ---------------- alpha for layer 1: wave per node, 256-wide rows ----------------
__global__ __launch_bounds__(256) void alpha1_kernel(const float* __restrict__ h1,
                                                     const float* __restrict__ a_src,
                                                     const float* __restrict__ a_dst,
                                                     float* __restrict__ as_out,
                                                     float* __restrict__ ad_out, int N) {
  int wid = (int)((blockIdx.x * (size_t)blockDim.x + threadIdx.x) >> 6);
  int lane = threadIdx.x & 63;
  if (wid >= N) return;
  float4 hv = *(const float4*)&h1[(size_t)wid * 256 + lane * 4];
  float4 sv = *(const float4*)&a_src[lane * 4];  // [8,32] flat: h*32+c == lane*4
  float4 dv = *(const float4*)&a_dst[lane * 4];
  float ps = hv.x * sv.x + hv.y * sv.y + hv.z * sv.z + hv.w * sv.w;
  float pd = hv.x * dv.x + hv.y * dv.y + hv.z * dv.z + hv.w * dv.w;
  ps += __shfl_xor(ps, 1); ps += __shfl_xor(ps, 2); ps += __shfl_xor(ps, 4);
  pd += __shfl_xor(pd, 1); pd += __shfl_xor(pd, 2); pd += __shfl_xor(pd, 4);
  if ((lane & 7) == 0) {
    as_out[wid * 8 + (lane >> 3)] = ps;
    ad_out[wid * 8 + (lane >> 3)] = pd;
  }
}

// ---------------- aggregation layer 1: wave per destination node ----------------
// lane l owns h[head=l>>3][c=(l&7)*4 .. +3].
// Softmax without max-subtraction: shift-invariant, |e| <= ~5 with this data,
// fminf(e,80) guards overflow. All per-edge updates are independent FMAs ->
// compiler can pipeline loads across the batch (no serial rescale chain).
__global__ __launch_bounds__(256) void agg1_kernel(const int* __restrict__ offs,
                                                   const int* __restrict__ csr,
                                                   const float* __restrict__ h1,
                                                   const float* __restrict__ as1,
                                                   const float* __restrict__ ad1,
                                                   const float* __restrict__ b1,
                                                   float* __restrict__ h2, int N) {
  int wid = (int)((blockIdx.x * (size_t)blockDim.x + threadIdx.x) >> 6);
  int lane = threadIdx.x & 63;
  if (wid >= N) return;
  int head = lane >> 3;

  float ad = ad1[wid * 8 + head];
  // self loop (src == dst)
  float p0 = __expf(fminf(leaky(as1[wid * 8 + head] + ad), 80.0f));
  float s = p0;
  float4 acc0 = *(const float4*)&h1[(size_t)wid * 256 + lane * 4];
  float4 acc;
  acc.x = p0 * acc0.x; acc.y = p0 * acc0.y; acc.z = p0 * acc0.z; acc.w = p0 * acc0.w;

  auto step = [&](float a0, const float4& hv) {
    float p = __expf(fminf(leaky(a0 + ad), 80.0f));
    s += p;
    acc.x = fmaf(p, hv.x, acc.x);
    acc.y = fmaf(p, hv.y, acc.y);
    acc.z = fmaf(p, hv.z, acc.z);
    acc.w = fmaf(p, hv.w, acc.w);
  };

  int j0 = offs[wid], j1 = offs[wid + 1];
  int j = j0;
  // batch-of-4: all 12 loads issued before any consumption
  for (; j + 4 <= j1; j += 4) {
    int s0 = csr[j], s1 = csr[j + 1], s2 = csr[j + 2], s3 = csr[j + 3];
    float a0 = as1[s0 * 8 + head];
    float a1 = as1[s1 * 8 + head];
    float a2 = as1[s2 * 8 + head];
    float a3 = as1[s3 * 8 + head];
    float4 h0 = *(const float4*)&h1[(size_t)s0 * 256 + lane * 4];
    float4 hv1 = *(const float4*)&h1[(size_t)s1 * 256 + lane * 4];
    float4 hv2 = *(const float4*)&h1[(size_t)s2 * 256 + lane * 4];
    float4 hv3 = *(const float4*)&h1[(size_t)s3 * 256 + lane * 4];
    step(a0, h0);
    step(a1, hv1);
    step(a2, hv2);
    step(a3, hv3);
  }
  for (; j < j1; ++j) {
    int s0 = csr[j];
    float a0 = as1[s0 * 8 + head];
    float4 h0 = *(const float4*)&h1[(size_t)s0 * 256 + lane * 4];
    step(a0, h0);
  }

  float rs = 1.0f / (s + 1e-16f);
  float4 bv = *(const float4*)&b1[lane * 4];
  float4 o;
  o.x = fmaxf(fmaf(acc.x, rs, bv.x), 0.0f);
  o.y = fmaxf(fmaf(acc.y, rs, bv.y), 0.0f);
  o.z = fmaxf(fmaf(acc.z, rs, bv.z), 0.0f);
  o.w = fmaxf(fmaf(acc.w, rs, bv.w), 0.0f);
  *(float4*)&h2[(size_t)wid * 256 + lane * 4] = o;
}

// ---------------- alpha for layer 2 (H=1, C=32): wave per node ----------------
__global__ __launch_bounds__(256) void alpha2_kernel(const float* __restrict__ hl2,
                                                     const float* __restrict__ a_src,
                                                     const float* __restrict__ a_dst,
                                                     float* __restrict__ as2,
                                                     float* __restrict__ ad2, int N) {
  int wid = (int)((blockIdx.x * (size_t)blockDim.x + threadIdx.x) >> 6);
  int lane = threadIdx.x & 63;
  if (wid >= N) return;
  int c = lane & 31;
  float w = (lane < 32) ? a_src[c] : a_dst[c];
  float v = hl2[(size_t)wid * 32 + c];
  float p = v * w;
  p += __shfl_xor(p, 1); p += __shfl_xor(p, 2); p += __shfl_xor(p, 4);
  p += __shfl_xor(p, 8); p += __shfl_xor(p, 16);
  if (lane == 0) as2[wid] = p;
  if (lane == 32) ad2[wid] = p;
}

// ---------------- aggregation layer 2: wave per node, C=32 ----------------
__global__ __launch_bounds__(256) void agg2_kernel(const int* __restrict__ offs,
                                                   const int* __restrict__ csr,
                                                   const float* __restrict__ hl2,
                                                   const float* __restrict__ as2,
                                                   const float* __restrict__ ad2,
                                                   const float* __restrict__ b2,
                                                   float* __restrict__ z, int N) {
  int wid = (int)((blockIdx.x * (size_t)blockDim.x + threadIdx.x) >> 6);
  int lane = threadIdx.x & 63;
  if (wid >= N) return;
  int c = lane & 31;

  float ad = ad2[wid];
  float p0 = __expf(fminf(leaky(as2[wid] + ad), 80.0f));
  float s = p0;
  float acc = p0 * hl2[(size_t)wid * 32 + c];

  auto step = [&](float a0, float v0) {
    float p = __expf(fminf(leaky(a0 + ad), 80.0f));
    s += p;
    acc = fmaf(p, v0, acc);
  };

  int j0 = offs[wid], j1 = offs[wid + 1];
  int j = j0;
  for (; j + 4 <= j1; j += 4) {
    int s0 = csr[j], s1 = csr[j + 1], s2 = csr[j + 2], s3 = csr[j + 3];
    float a0 = as2[s0], a1 = as2[s1], a2 = as2[s2], a3 = as2[s3];
    float v0 = hl2[(size_t)s0 * 32 + c];
    float v1 = hl2[(size_t)s1 * 32 + c];
    float v2 = hl2[(size_t)s2 * 32 + c];
    float v3 = hl2[(size_t)s3 * 32 + c];
    step(a0, v0);
    step(a1, v1);
    step(a2, v2);
    step(a3, v3);
  }
  for (; j < j1; ++j) {
    int s0 = csr[j];
    step(as2[s0], hl2[(size_t)s0 * 32 + c]);
  }

  if (lane < 32) {
    float rs = 1.0f / (s + 1e-16f);
    z[(size_t)wid * 32 + c] = fmaf(acc, rs, b2[c]);
  }
}

// ---------------- launch ----------------
extern "C" void kernel_launch(void* const* d_in, const int* in_sizes, int n_in,
                              void* d_out, int out_size, void* d_ws, size_t ws_size,
                              hipStream_t stream) {
  const float* x = (const float*)d_in[0];
  const int* ei = (const int*)d_in[1];  // [2, E]
  const float* W1 = (const float*)d_in[2];
  const float* a_src1 = (const float*)d_in[3];
  const float* a_dst1 = (const float*)d_in[4];
  const float* b1 = (const float*)d_in[5];
  const float* W2 = (const float*)d_in[6];
  const float* a_src2 = (const float*)d_in[7];
  const float* a_dst2 = (const float*)d_in[8];
  const float* b2 = (const float*)d_in[9];
  const float* Wd = (const float*)d_in[10];
  const float* bd = (const float*)d_in[11];
  float* out = (float*)d_out;

  const int IN = 128, HC1 = 256, C2 = 32, OUT = 128;
  int N = in_sizes[0] / IN;
  int E = in_sizes[1] / 2;

  // workspace carve
  char* p = (char*)d_ws;
  auto alloc = [&](size_t bytes) {
    void* r = (void*)p;
    p += (bytes + 255) & ~(size_t)255;
    return r;
  };
  float* h1 = (float*)alloc((size_t)N * HC1 * 4);
  float* as1 = (float*)alloc((size_t)N * 8 * 4);
  float* ad1 = (float*)alloc((size_t)N * 8 * 4);
  float* h2 = (float*)alloc((size_t)N * HC1 * 4);
  float* hl2 = (float*)alloc((size_t)N * C2 * 4);
  float* as2 = (float*)alloc((size_t)N * 4);
  float* ad2 = (float*)alloc((size_t)N * 4);
  float* z = (float*)alloc((size_t)N * C2 * 4);
  int* counts = (int*)alloc((size_t)N * 4);
  int* cursor = (int*)alloc((size_t)N * 4);
  int* offs = (int*)alloc((size_t)(N + 1) * 4);
  int* csr = (int*)alloc((size_t)E * 4);

  int nblk = (N + 255) / 256;
  int eblk = (E + 255) / 256;
  int wblk = (int)(((size_t)N * 64 + 255) / 256);  // wave-per-node kernels

  // CSR build
  zero_kernel<<<nblk, 256, 0, stream>>>(counts, N);
  count_kernel<<<eblk, 256, 0, stream>>>(ei, counts, E);
  scan_kernel<<<1, 1024, 0, stream>>>(counts, offs, cursor, N);
  fill_kernel<<<eblk, 256, 0, stream>>>(ei, cursor, csr, E);

  // layer 1
  {
    dim3 g((N + 63) / 64, HC1 / 64);
    gemm_tiled<false><<<g, 256, 0, stream>>>(x, W1, nullptr, h1, N, HC1, IN);
  }
  alpha1_kernel<<<wblk, 256, 0, stream>>>(h1, a_src1, a_dst1, as1, ad1, N);
  agg1_kernel<<<wblk, 256, 0, stream>>>(offs, csr, h1, as1, ad1, b1, h2, N);

  // layer 2
  {
    dim3 g((N + 63) / 64, 1);
    gemm_tiled<false><<<g, 256, 0, stream>>>(h2, W2, nullptr, hl2, N, C2, HC1);
  }
  alpha2_kernel<<<wblk, 256, 0, stream>>>(hl2, a_src2, a_dst2, as2, ad2, N);
  agg2_kernel<<<wblk, 256, 0, stream>>>(offs, csr, hl2, as2, ad2, b2, z, N);

  // decode
  {
    dim3 g((N + 63) / 64, OUT / 64);
    gemm_tiled<true><<<g, 256, 0, stream>>>(z, Wd, bd, out, N, OUT, C2);
  }
}

// Round 13
// 559.288 us; speedup vs baseline: 1.0227x; 1.0227x over previous
//
#include <hip/hip_runtime.h>
#include <math.h>

#define NEG_SLOPE 0.2f

typedef float f32x4_t __attribute__((ext_vector_type(4)));

static __device__ __forceinline__ float leaky(float x) {
  return x > 0.0f ? x : NEG_SLOPE * x;
}

static __device__ __forceinline__ void nt_store4(float* p, float a, float b, float c, float d) {
  f32x4_t v = {a, b, c, d};
  __builtin_nontemporal_store(v, (f32x4_t*)p);
}

// ---------------- CSR build ----------------
__global__ void zero_kernel(int* __restrict__ p, int n) {
  int i = blockIdx.x * blockDim.x + threadIdx.x;
  if (i < n) p[i] = 0;
}

__global__ void count_kernel(const int* __restrict__ ei, int* __restrict__ counts, int E) {
  int i = blockIdx.x * blockDim.x + threadIdx.x;
  if (i < E) atomicAdd(&counts[ei[E + i]], 1);
}

// single block, 1024 threads: exclusive scan of counts -> offs, cursor
__global__ void scan_kernel(const int* __restrict__ counts, int* __restrict__ offs,
                            int* __restrict__ cursor, int N) {
  __shared__ int sums[1024];
  int tid = threadIdx.x;
  int chunk = (N + 1023) >> 10;
  int start = tid * chunk;
  int end = min(start + chunk, N);
  int s = 0;
  for (int i = start; i < end; ++i) s += counts[i];
  sums[tid] = s;
  __syncthreads();
  for (int off = 1; off < 1024; off <<= 1) {
    int v = (tid >= off) ? sums[tid - off] : 0;
    __syncthreads();
    sums[tid] += v;
    __syncthreads();
  }
  int run = (tid > 0) ? sums[tid - 1] : 0;
  for (int i = start; i < end; ++i) {
    offs[i] = run;
    cursor[i] = run;
    run += counts[i];
  }
  if (tid == 0) offs[N] = sums[1023];
}

__global__ void fill_kernel(const int* __restrict__ ei, int* __restrict__ cursor,
                            int* __restrict__ csr, int E) {
  int i = blockIdx.x * blockDim.x + threadIdx.x;
  if (i < E) {
    int src = ei[i];
    int dst = ei[E + i];
    int pos = atomicAdd(&cursor[dst], 1);
    csr[pos] = src;
  }
}

// ---------------- 64x64-tile f32 GEMM (used for N=32 layer-2 matmul) ----------------
template <bool BIAS>
__global__ __launch_bounds__(256) void gemm_tiled(const float* __restrict__ A,
                                                  const float* __restrict__ B,
                                                  const float* __restrict__ bias,
                                                  float* __restrict__ C,
                                                  int M, int N, int K) {
  __shared__ float As[16][68];  // transposed: As[k][m]
  __shared__ float Bs[16][68];
  int tid = threadIdx.x;
  int tx = tid & 15, ty = tid >> 4;
  int brow = blockIdx.x * 64, bcol = blockIdx.y * 64;

  float acc[4][4] = {};

  int arow = tid >> 2;         // 0..63
  int akv = (tid & 3) * 4;     // 0,4,8,12
  int bkk = tid >> 4;          // 0..15
  int bcv = (tid & 15) * 4;    // 0..60

  for (int k0 = 0; k0 < K; k0 += 16) {
    int gr = min(brow + arow, M - 1);
    float4 av = *(const float4*)&A[(size_t)gr * K + k0 + akv];
    float4 bv;
    int gc = bcol + bcv;
    if (gc + 3 < N)
      bv = *(const float4*)&B[(size_t)(k0 + bkk) * N + gc];
    else
      bv = make_float4(0.f, 0.f, 0.f, 0.f);

    __syncthreads();
    As[akv + 0][arow] = av.x;
    As[akv + 1][arow] = av.y;
    As[akv + 2][arow] = av.z;
    As[akv + 3][arow] = av.w;
    *(float4*)&Bs[bkk][bcv] = bv;
    __syncthreads();

#pragma unroll
    for (int kk = 0; kk < 16; ++kk) {
      float4 a4 = *(const float4*)&As[kk][ty * 4];
      float4 b4 = *(const float4*)&Bs[kk][tx * 4];
      float ar[4] = {a4.x, a4.y, a4.z, a4.w};
      float br[4] = {b4.x, b4.y, b4.z, b4.w};
#pragma unroll
      for (int i = 0; i < 4; ++i)
#pragma unroll
        for (int j = 0; j < 4; ++j) acc[i][j] = fmaf(ar[i], br[j], acc[i][j]);
    }
  }

#pragma unroll
  for (int i = 0; i < 4; ++i) {
    int r = brow + ty * 4 + i;
    if (r >= M) continue;
#pragma unroll
    for (int j = 0; j < 4; ++j) {
      int c = bcol + tx * 4 + j;
      if (c >= N) continue;
      float v = acc[i][j];
      if (BIAS) v += bias[c];
      C[(size_t)r * N + c] = v;
    }
  }
}

// ---------------- 128x128-tile / 8x8-micro f32 GEMM ----------------
// Requires N % 128 == 0, K % 16 == 0. blockIdx.x = col tile, blockIdx.y = row tile.
// Linear LDS (no swizzle): the 4-way conflict on Bs b128 reads is hidden behind
// the 128-cycle/kk FMA issue stream (VALU-bound), and a broken swizzle cost us
// a round — keep it simple and bijective-by-construction.
template <bool BIAS>
__global__ __launch_bounds__(256) void gemm_big(const float* __restrict__ A,
                                                const float* __restrict__ B,
                                                const float* __restrict__ bias,
                                                float* __restrict__ C,
                                                int M, int N, int K) {
  __shared__ float As[16][128];  // As[k][m] (transposed)
  __shared__ float Bs[16][128];  // Bs[k][col] (linear)
  int tid = threadIdx.x;
  int tx = tid & 15, ty = tid >> 4;
  int brow = blockIdx.y * 128, bcol = blockIdx.x * 128;

  float acc[8][8] = {};

  int ar = tid >> 1;          // 0..127
  int akv = (tid & 1) * 8;    // 0 or 8
  int bk = tid >> 4;          // 0..15
  int bcv = (tid & 15) * 8;   // 0..120

  const float* Aptr = A + (size_t)min(brow + ar, M - 1) * K + akv;
  const float* Bptr = B + (size_t)bk * N + bcol + bcv;

  for (int k0 = 0; k0 < K; k0 += 16) {
    float4 a0 = *(const float4*)(Aptr + k0);
    float4 a1 = *(const float4*)(Aptr + k0 + 4);
    float4 b0 = *(const float4*)(Bptr + (size_t)k0 * N);
    float4 b1 = *(const float4*)(Bptr + (size_t)k0 * N + 4);

    __syncthreads();
    As[akv + 0][ar] = a0.x;
    As[akv + 1][ar] = a0.y;
    As[akv + 2][ar] = a0.z;
    As[akv + 3][ar] = a0.w;
    As[akv + 4][ar] = a1.x;
    As[akv + 5][ar] = a1.y;
    As[akv + 6][ar] = a1.z;
    As[akv + 7][ar] = a1.w;
    *(float4*)&Bs[bk][bcv] = b0;
    *(float4*)&Bs[bk][bcv + 4] = b1;
    __syncthreads();

#pragma unroll
    for (int kk = 0; kk < 16; ++kk) {
      float4 av0 = *(const float4*)&As[kk][ty * 8];
      float4 av1 = *(const float4*)&As[kk][ty * 8 + 4];
      float4 bv0 = *(const float4*)&Bs[kk][tx * 8];
      float4 bv1 = *(const float4*)&Bs[kk][tx * 8 + 4];
      float ar8[8] = {av0.x, av0.y, av0.z, av0.w, av1.x, av1.y, av1.z, av1.w};
      float br8[8] = {bv0.x, bv0.y, bv0.z, bv0.w, bv1.x, bv1.y, bv1.z, bv1.w};
#pragma unroll
      for (int i = 0; i < 8; ++i)
#pragma unroll
        for (int j = 0; j < 8; ++j) acc[i][j] = fmaf(ar8[i], br8[j], acc[i][j]);
    }
  }

#pragma unroll
  for (int i = 0; i < 8; ++i) {
    int r = brow + ty * 8 + i;
    if (r >= M) continue;
#pragma unroll
    for (int j0 = 0; j0 < 8; j0 += 4) {
      int c = bcol + tx * 8 + j0;
      float4 v = {acc[i][j0], acc[i][j0 + 1], acc[i][j0 + 2], acc[i][j0 + 3]};
      if (BIAS) {
        float4 bb = *(const float4*)&bias[c];
        v.x += bb.x; v.y += bb.y; v.z += bb.z; v.w += bb.w;
      }
      *(float4*)&C[(size_t)r * N + c] = v;
    }
  }
}

// ---------------- alpha for layer 1: wave per node, 256-wide rows ----------------
__global__ __launch_bounds__(256) void alpha1_kernel(const float* __restrict__ h1,
                                                     const float* __restrict__ a_src,
                                                     const float* __restrict__ a_dst,
                                                     float* __restrict__ as_out,
                                                     float* __restrict__ ad_out, int N) {
  int wid = (int)((blockIdx.x * (size_t)blockDim.x + threadIdx.x) >> 6);
  int lane = threadIdx.x & 63;
  if (wid >= N) return;
  float4 hv = *(const float4*)&h1[(size_t)wid * 256 + lane * 4];
  float4 sv = *(const float4*)&a_src[lane * 4];  // [8,32] flat: h*32+c == lane*4
  float4 dv = *(const float4*)&a_dst[lane * 4];
  float ps = hv.x * sv.x + hv.y * sv.y + hv.z * sv.z + hv.w * sv.w;
  float pd = hv.x * dv.x + hv.y * dv.y + hv.z * dv.z + hv.w * dv.w;
  ps += __shfl_xor(ps, 1); ps += __shfl_xor(ps, 2); ps += __shfl_xor(ps, 4);
  pd += __shfl_xor(pd, 1); pd += __shfl_xor(pd, 2); pd += __shfl_xor(pd, 4);
  if ((lane & 7) == 0) {
    as_out[wid * 8 + (lane >> 3)] = ps;
    ad_out[wid * 8 + (lane >> 3)] = pd;
  }
}

// ---------------- aggregation layer 1: wave per destination node ----------------
// lane l owns h[head=l>>3][c=(l&7)*4 .. +3].
// Softmax without max-subtraction (shift-invariant; |e| bounded ~5 with this data;
// fminf(e,80) overflow guard). Batch-8 gather: 24 loads in flight per wave.
__global__ __launch_bounds__(256) void agg1_kernel(const int* __restrict__ offs,
                                                   const int* __restrict__ csr,
                                                   const float* __restrict__ h1,
                                                   const float* __restrict__ as1,
                                                   const float* __restrict__ ad1,
                                                   const float* __restrict__ b1,
                                                   float* __restrict__ h2, int N) {
  int wid = (int)((blockIdx.x * (size_t)blockDim.x + threadIdx.x) >> 6);
  int lane = threadIdx.x & 63;
  if (wid >= N) return;
  int head = lane >> 3;

  float ad = ad1[wid * 8 + head];
  // self loop (src == dst)
  float p0 = __expf(fminf(leaky(as1[wid * 8 + head] + ad), 80.0f));
  float s = p0;
  float4 acc0 = *(const float4*)&h1[(size_t)wid * 256 + lane * 4];
  float4 acc;
  acc.x = p0 * acc0.x; acc.y = p0 * acc0.y; acc.z = p0 * acc0.z; acc.w = p0 * acc0.w;

  auto step = [&](float a0, const float4& hv) {
    float p = __expf(fminf(leaky(a0 + ad), 80.0f));
    s += p;
    acc.x = fmaf(p, hv.x, acc.x);
    acc.y = fmaf(p, hv.y, acc.y);
    acc.z = fmaf(p, hv.z, acc.z);
    acc.w = fmaf(p, hv.w, acc.w);
  };

  int j0 = offs[wid], j1 = offs[wid + 1];
  int j = j0;
  for (; j + 8 <= j1; j += 8) {
    int si[8];
    float a[8];
    float4 hv[8];
#pragma unroll
    for (int u = 0; u < 8; ++u) si[u] = csr[j + u];
#pragma unroll
    for (int u = 0; u < 8; ++u) a[u] = as1[si[u] * 8 + head];
#pragma unroll
    for (int u = 0; u < 8; ++u) hv[u] = *(const float4*)&h1[(size_t)si[u] * 256 + lane * 4];
#pragma unroll
    for (int u = 0; u < 8; ++u) step(a[u], hv[u]);
  }
  for (; j + 4 <= j1; j += 4) {
    int si[4];
    float a[4];
    float4 hv[4];
#pragma unroll
    for (int u = 0; u < 4; ++u) si[u] = csr[j + u];
#pragma unroll
    for (int u = 0; u < 4; ++u) a[u] = as1[si[u] * 8 + head];
#pragma unroll
    for (int u = 0; u < 4; ++u) hv[u] = *(const float4*)&h1[(size_t)si[u] * 256 + lane * 4];
#pragma unroll
    for (int u = 0; u < 4; ++u) step(a[u], hv[u]);
  }
  for (; j < j1; ++j) {
    int s0 = csr[j];
    float a0 = as1[s0 * 8 + head];
    float4 h0 = *(const float4*)&h1[(size_t)s0 * 256 + lane * 4];
    step(a0, h0);
  }

  float rs = 1.0f / (s + 1e-16f);
  float4 bv = *(const float4*)&b1[lane * 4];
  // non-temporal: don't let the 50MB h2 stream evict h1 gather lines from L2
  nt_store4(&h2[(size_t)wid * 256 + lane * 4],
            fmaxf(fmaf(acc.x, rs, bv.x), 0.0f),
            fmaxf(fmaf(acc.y, rs, bv.y), 0.0f),
            fmaxf(fmaf(acc.z, rs, bv.z), 0.0f),
            fmaxf(fmaf(acc.w, rs, bv.w), 0.0f));
}

// ---------------- alpha for layer 2 (H=1, C=32): wave per node ----------------
__global__ __launch_bounds__(256) void alpha2_kernel(const float* __restrict__ hl2,
                                                     const float* __restrict__ a_src,
                                                     const float* __restrict__ a_dst,
                                                     float* __restrict__ as2,
                                                     float* __restrict__ ad2, int N) {
  int wid = (int)((blockIdx.x * (size_t)blockDim.x + threadIdx.x) >> 6);
  int lane = threadIdx.x & 63;
  if (wid >= N) return;
  int c = lane & 31;
  float w = (lane < 32) ? a_src[c] : a_dst[c];
  float v = hl2[(size_t)wid * 32 + c];
  float p = v * w;
  p += __shfl_xor(p, 1); p += __shfl_xor(p, 2); p += __shfl_xor(p, 4);
  p += __shfl_xor(p, 8); p += __shfl_xor(p, 16);
  if (lane == 0) as2[wid] = p;
  if (lane == 32) ad2[wid] = p;
}

// ---------------- aggregation layer 2: wave per node, C=32 ----------------
__global__ __launch_bounds__(256) void agg2_kernel(const int* __restrict__ offs,
                                                   const int* __restrict__ csr,
                                                   const float* __restrict__ hl2,
                                                   const float* __restrict__ as2,
                                                   const float* __restrict__ ad2,
                                                   const float* __restrict__ b2,
                                                   float* __restrict__ z, int N) {
  int wid = (int)((blockIdx.x * (size_t)blockDim.x + threadIdx.x) >> 6);
  int lane = threadIdx.x & 63;
  if (wid >= N) return;
  int c = lane & 31;

  float ad = ad2[wid];
  float p0 = __expf(fminf(leaky(as2[wid] + ad), 80.0f));
  float s = p0;
  float acc = p0 * hl2[(size_t)wid * 32 + c];

  auto step = [&](float a0, float v0) {
    float p = __expf(fminf(leaky(a0 + ad), 80.0f));
    s += p;
    acc = fmaf(p, v0, acc);
  };

  int j0 = offs[wid], j1 = offs[wid + 1];
  int j = j0;
  for (; j + 8 <= j1; j += 8) {
    int si[8];
    float a[8], v[8];
#pragma unroll
    for (int u = 0; u < 8; ++u) si[u] = csr[j + u];
#pragma unroll
    for (int u = 0; u < 8; ++u) a[u] = as2[si[u]];
#pragma unroll
    for (int u = 0; u < 8; ++u) v[u] = hl2[(size_t)si[u] * 32 + c];
#pragma unroll
    for (int u = 0; u < 8; ++u) step(a[u], v[u]);
  }
  for (; j < j1; ++j) {
    int s0 = csr[j];
    step(as2[s0], hl2[(size_t)s0 * 32 + c]);
  }

  if (lane < 32) {
    float rs = 1.0f / (s + 1e-16f);
    z[(size_t)wid * 32 + c] = fmaf(acc, rs, b2[c]);
  }
}

// ---------------- launch ----------------
extern "C" void kernel_launch(void* const* d_in, const int* in_sizes, int n_in,
                              void* d_out, int out_size, void* d_ws, size_t ws_size,
                              hipStream_t stream) {
  const float* x = (const float*)d_in[0];
  const int* ei = (const int*)d_in[1];  // [2, E]
  const float* W1 = (const float*)d_in[2];
  const float* a_src1 = (const float*)d_in[3];
  const float* a_dst1 = (const float*)d_in[4];
  const float* b1 = (const float*)d_in[5];
  const float* W2 = (const float*)d_in[6];
  const float* a_src2 = (const float*)d_in[7];
  const float* a_dst2 = (const float*)d_in[8];
  const float* b2 = (const float*)d_in[9];
  const float* Wd = (const float*)d_in[10];
  const float* bd = (const float*)d_in[11];
  float* out = (float*)d_out;

  const int IN = 128, HC1 = 256, C2 = 32, OUT = 128;
  int N = in_sizes[0] / IN;
  int E = in_sizes[1] / 2;

  // workspace carve
  char* p = (char*)d_ws;
  auto alloc = [&](size_t bytes) {
    void* r = (void*)p;
    p += (bytes + 255) & ~(size_t)255;
    return r;
  };
  float* h1 = (float*)alloc((size_t)N * HC1 * 4);
  float* as1 = (float*)alloc((size_t)N * 8 * 4);
  float* ad1 = (float*)alloc((size_t)N * 8 * 4);
  float* h2 = (float*)alloc((size_t)N * HC1 * 4);
  float* hl2 = (float*)alloc((size_t)N * C2 * 4);
  float* as2 = (float*)alloc((size_t)N * 4);
  float* ad2 = (float*)alloc((size_t)N * 4);
  float* z = (float*)alloc((size_t)N * C2 * 4);
  int* counts = (int*)alloc((size_t)N * 4);
  int* cursor = (int*)alloc((size_t)N * 4);
  int* offs = (int*)alloc((size_t)(N + 1) * 4);
  int* csr = (int*)alloc((size_t)E * 4);

  int nblk = (N + 255) / 256;
  int eblk = (E + 255) / 256;
  int wblk = (int)(((size_t)N * 64 + 255) / 256);  // wave-per-node kernels

  // CSR build
  zero_kernel<<<nblk, 256, 0, stream>>>(counts, N);
  count_kernel<<<eblk, 256, 0, stream>>>(ei, counts, E);
  scan_kernel<<<1, 1024, 0, stream>>>(counts, offs, cursor, N);
  fill_kernel<<<eblk, 256, 0, stream>>>(ei, cursor, csr, E);

  // layer 1: h1 = x @ W1   (M=N nodes, N=256, K=128)
  {
    dim3 g(HC1 / 128, (N + 127) / 128);
    gemm_big<false><<<g, 256, 0, stream>>>(x, W1, nullptr, h1, N, HC1, IN);
  }
  alpha1_kernel<<<wblk, 256, 0, stream>>>(h1, a_src1, a_dst1, as1, ad1, N);
  agg1_kernel<<<wblk, 256, 0, stream>>>(offs, csr, h1, as1, ad1, b1, h2, N);

  // layer 2: hl2 = h2 @ W2   (N=32 -> 64x64 kernel with guards)
  {
    dim3 g((N + 63) / 64, 1);
    gemm_tiled<false><<<g, 256, 0, stream>>>(h2, W2, nullptr, hl2, N, C2, HC1);
  }
  alpha2_kernel<<<wblk, 256, 0, stream>>>(hl2, a_src2, a_dst2, as2, ad2, N);
  agg2_kernel<<<wblk, 256, 0, stream>>>(offs, csr, hl2, as2, ad2, b2, z, N);

  // decode: out = z @ Wd + bd   (N=128, K=32)
  {
    dim3 g(OUT / 128, (N + 127) / 128);
    gemm_big<true><<<g, 256, 0, stream>>>(z, Wd, bd, out, N, OUT, C2);
  }
}

// Round 15
// 496.199 us; speedup vs baseline: 1.1528x; 1.1271x over previous
//
#include <hip/hip_runtime.h>
#include <math.h>

#define NEG_SLOPE 0.2f

typedef float f32x4_t __attribute__((ext_vector_type(4)));

static __device__ __forceinline__ float leaky(float x) {
  return x > 0.0f ? x : NEG_SLOPE * x;
}

static __device__ __forceinline__ void nt_store4(float* p, float a, float b, float c, float d) {
  f32x4_t v = {a, b, c, d};
  __builtin_nontemporal_store(v, (f32x4_t*)p);
}

// bf16 helpers (RNE)
static __device__ __forceinline__ unsigned short f32_to_bf16(float f) {
  unsigned int u = __float_as_uint(f);
  unsigned int r = u + 0x7FFFu + ((u >> 16) & 1u);
  return (unsigned short)(r >> 16);
}
static __device__ __forceinline__ float bf16_to_f32(unsigned short h) {
  return __uint_as_float(((unsigned int)h) << 16);
}

// ---------------- CSR build ----------------
__global__ void zero_kernel(int* __restrict__ p, int n) {
  int i = blockIdx.x * blockDim.x + threadIdx.x;
  if (i < n) p[i] = 0;
}

__global__ void count_kernel(const int* __restrict__ ei, int* __restrict__ counts, int E) {
  int i = blockIdx.x * blockDim.x + threadIdx.x;
  if (i < E) atomicAdd(&counts[ei[E + i]], 1);
}

// single block, 1024 threads: exclusive scan of counts -> offs, cursor
__global__ void scan_kernel(const int* __restrict__ counts, int* __restrict__ offs,
                            int* __restrict__ cursor, int N) {
  __shared__ int sums[1024];
  int tid = threadIdx.x;
  int chunk = (N + 1023) >> 10;
  int start = tid * chunk;
  int end = min(start + chunk, N);
  int s = 0;
  for (int i = start; i < end; ++i) s += counts[i];
  sums[tid] = s;
  __syncthreads();
  for (int off = 1; off < 1024; off <<= 1) {
    int v = (tid >= off) ? sums[tid - off] : 0;
    __syncthreads();
    sums[tid] += v;
    __syncthreads();
  }
  int run = (tid > 0) ? sums[tid - 1] : 0;
  for (int i = start; i < end; ++i) {
    offs[i] = run;
    cursor[i] = run;
    run += counts[i];
  }
  if (tid == 0) offs[N] = sums[1023];
}

__global__ void fill_kernel(const int* __restrict__ ei, int* __restrict__ cursor,
                            int* __restrict__ csr, int E) {
  int i = blockIdx.x * blockDim.x + threadIdx.x;
  if (i < E) {
    int src = ei[i];
    int dst = ei[E + i];
    int pos = atomicAdd(&cursor[dst], 1);
    csr[pos] = src;
  }
}

// ---------------- 64x64-tile f32 GEMM (used for N=32 layer-2 matmul) ----------------
template <bool BIAS>
__global__ __launch_bounds__(256) void gemm_tiled(const float* __restrict__ A,
                                                  const float* __restrict__ B,
                                                  const float* __restrict__ bias,
                                                  float* __restrict__ C,
                                                  int M, int N, int K) {
  __shared__ float As[16][68];  // transposed: As[k][m]
  __shared__ float Bs[16][68];
  int tid = threadIdx.x;
  int tx = tid & 15, ty = tid >> 4;
  int brow = blockIdx.x * 64, bcol = blockIdx.y * 64;

  float acc[4][4] = {};

  int arow = tid >> 2;         // 0..63
  int akv = (tid & 3) * 4;     // 0,4,8,12
  int bkk = tid >> 4;          // 0..15
  int bcv = (tid & 15) * 4;    // 0..60

  for (int k0 = 0; k0 < K; k0 += 16) {
    int gr = min(brow + arow, M - 1);
    float4 av = *(const float4*)&A[(size_t)gr * K + k0 + akv];
    float4 bv;
    int gc = bcol + bcv;
    if (gc + 3 < N)
      bv = *(const float4*)&B[(size_t)(k0 + bkk) * N + gc];
    else
      bv = make_float4(0.f, 0.f, 0.f, 0.f);

    __syncthreads();
    As[akv + 0][arow] = av.x;
    As[akv + 1][arow] = av.y;
    As[akv + 2][arow] = av.z;
    As[akv + 3][arow] = av.w;
    *(float4*)&Bs[bkk][bcv] = bv;
    __syncthreads();

#pragma unroll
    for (int kk = 0; kk < 16; ++kk) {
      float4 a4 = *(const float4*)&As[kk][ty * 4];
      float4 b4 = *(const float4*)&Bs[kk][tx * 4];
      float ar[4] = {a4.x, a4.y, a4.z, a4.w};
      float br[4] = {b4.x, b4.y, b4.z, b4.w};
#pragma unroll
      for (int i = 0; i < 4; ++i)
#pragma unroll
        for (int j = 0; j < 4; ++j) acc[i][j] = fmaf(ar[i], br[j], acc[i][j]);
    }
  }

#pragma unroll
  for (int i = 0; i < 4; ++i) {
    int r = brow + ty * 4 + i;
    if (r >= M) continue;
#pragma unroll
    for (int j = 0; j < 4; ++j) {
      int c = bcol + tx * 4 + j;
      if (c >= N) continue;
      float v = acc[i][j];
      if (BIAS) v += bias[c];
      C[(size_t)r * N + c] = v;
    }
  }
}

// ---------------- 128x128-tile / 8x8-micro f32 GEMM ----------------
// Requires N % 128 == 0, K % 16 == 0. Linear LDS (bijective by construction).
// OUT_BF16: RNE-convert the f32 accumulator and store 16-bit (used for h1).
template <bool BIAS, bool OUT_BF16>
__global__ __launch_bounds__(256) void gemm_big(const float* __restrict__ A,
                                                const float* __restrict__ B,
                                                const float* __restrict__ bias,
                                                float* __restrict__ C,
                                                unsigned short* __restrict__ C16,
                                                int M, int N, int K) {
  __shared__ float As[16][128];  // As[k][m] (transposed)
  __shared__ float Bs[16][128];  // Bs[k][col] (linear)
  int tid = threadIdx.x;
  int tx = tid & 15, ty = tid >> 4;
  int brow = blockIdx.y * 128, bcol = blockIdx.x * 128;

  float acc[8][8] = {};

  int ar = tid >> 1;          // 0..127
  int akv = (tid & 1) * 8;    // 0 or 8
  int bk = tid >> 4;          // 0..15
  int bcv = (tid & 15) * 8;   // 0..120

  const float* Aptr = A + (size_t)min(brow + ar, M - 1) * K + akv;
  const float* Bptr = B + (size_t)bk * N + bcol + bcv;

  for (int k0 = 0; k0 < K; k0 += 16) {
    float4 a0 = *(const float4*)(Aptr + k0);
    float4 a1 = *(const float4*)(Aptr + k0 + 4);
    float4 b0 = *(const float4*)(Bptr + (size_t)k0 * N);
    float4 b1 = *(const float4*)(Bptr + (size_t)k0 * N + 4);

    __syncthreads();
    As[akv + 0][ar] = a0.x;
    As[akv + 1][ar] = a0.y;
    As[akv + 2][ar] = a0.z;
    As[akv + 3][ar] = a0.w;
    As[akv + 4][ar] = a1.x;
    As[akv + 5][ar] = a1.y;
    As[akv + 6][ar] = a1.z;
    As[akv + 7][ar] = a1.w;
    *(float4*)&Bs[bk][bcv] = b0;
    *(float4*)&Bs[bk][bcv + 4] = b1;
    __syncthreads();

#pragma unroll
    for (int kk = 0; kk < 16; ++kk) {
      float4 av0 = *(const float4*)&As[kk][ty * 8];
      float4 av1 = *(const float4*)&As[kk][ty * 8 + 4];
      float4 bv0 = *(const float4*)&Bs[kk][tx * 8];
      float4 bv1 = *(const float4*)&Bs[kk][tx * 8 + 4];
      float ar8[8] = {av0.x, av0.y, av0.z, av0.w, av1.x, av1.y, av1.z, av1.w};
      float br8[8] = {bv0.x, bv0.y, bv0.z, bv0.w, bv1.x, bv1.y, bv1.z, bv1.w};
#pragma unroll
      for (int i = 0; i < 8; ++i)
#pragma unroll
        for (int j = 0; j < 8; ++j) acc[i][j] = fmaf(ar8[i], br8[j], acc[i][j]);
    }
  }

#pragma unroll
  for (int i = 0; i < 8; ++i) {
    int r = brow + ty * 8 + i;
    if (r >= M) continue;
    if (OUT_BF16) {
      int c = bcol + tx * 8;
      ushort4 v0, v1;
      v0.x = f32_to_bf16(acc[i][0]);
      v0.y = f32_to_bf16(acc[i][1]);
      v0.z = f32_to_bf16(acc[i][2]);
      v0.w = f32_to_bf16(acc[i][3]);
      v1.x = f32_to_bf16(acc[i][4]);
      v1.y = f32_to_bf16(acc[i][5]);
      v1.z = f32_to_bf16(acc[i][6]);
      v1.w = f32_to_bf16(acc[i][7]);
      *(ushort4*)&C16[(size_t)r * N + c] = v0;
      *(ushort4*)&C16[(size_t)r * N + c + 4] = v1;
    } else {
#pragma unroll
      for (int j0 = 0; j0 < 8; j0 += 4) {
        int c = bcol + tx * 8 + j0;
        float4 v = {acc[i][j0], acc[i][j0 + 1], acc[i][j0 + 2], acc[i][j0 + 3]};
        if (BIAS) {
          float4 bb = *(const float4*)&bias[c];
          v.x += bb.x; v.y += bb.y; v.z += bb.z; v.w += bb.w;
        }
        *(float4*)&C[(size_t)r * N + c] = v;
      }
    }
  }
}

// ---------------- alpha for layer 1: wave per node, 256-wide bf16 rows ----------------
__global__ __launch_bounds__(256) void alpha1_kernel(const unsigned short* __restrict__ h1b,
                                                     const float* __restrict__ a_src,
                                                     const float* __restrict__ a_dst,
                                                     float* __restrict__ as_out,
                                                     float* __restrict__ ad_out, int N) {
  int wid = (int)((blockIdx.x * (size_t)blockDim.x + threadIdx.x) >> 6);
  int lane = threadIdx.x & 63;
  if (wid >= N) return;
  ushort4 hq = *(const ushort4*)&h1b[(size_t)wid * 256 + lane * 4];
  float4 sv = *(const float4*)&a_src[lane * 4];  // [8,32] flat: h*32+c == lane*4
  float4 dv = *(const float4*)&a_dst[lane * 4];
  float hx = bf16_to_f32(hq.x), hy = bf16_to_f32(hq.y);
  float hz = bf16_to_f32(hq.z), hw = bf16_to_f32(hq.w);
  float ps = hx * sv.x + hy * sv.y + hz * sv.z + hw * sv.w;
  float pd = hx * dv.x + hy * dv.y + hz * dv.z + hw * dv.w;
  ps += __shfl_xor(ps, 1); ps += __shfl_xor(ps, 2); ps += __shfl_xor(ps, 4);
  pd += __shfl_xor(pd, 1); pd += __shfl_xor(pd, 2); pd += __shfl_xor(pd, 4);
  if ((lane & 7) == 0) {
    as_out[wid * 8 + (lane >> 3)] = ps;
    ad_out[wid * 8 + (lane >> 3)] = pd;
  }
}

// ---------------- aggregation layer 1: wave per destination node, bf16 gather ----------
// lane l owns h[head=l>>3][c=(l&7)*4 .. +3]. Softmax without max-subtraction
// (shift-invariant; fminf(e,80) guard). Batch-8: 24 loads in flight per wave.
// h1 is bf16: halves the 800K x 1KB gather stream (the kernel's cost driver).
__global__ __launch_bounds__(256) void agg1_kernel(const int* __restrict__ offs,
                                                   const int* __restrict__ csr,
                                                   const unsigned short* __restrict__ h1b,
                                                   const float* __restrict__ as1,
                                                   const float* __restrict__ ad1,
                                                   const float* __restrict__ b1,
                                                   float* __restrict__ h2, int N) {
  int wid = (int)((blockIdx.x * (size_t)blockDim.x + threadIdx.x) >> 6);
  int lane = threadIdx.x & 63;
  if (wid >= N) return;
  int head = lane >> 3;

  float ad = ad1[wid * 8 + head];
  // self loop (src == dst)
  float p0 = __expf(fminf(leaky(as1[wid * 8 + head] + ad), 80.0f));
  float s = p0;
  ushort4 hq0 = *(const ushort4*)&h1b[(size_t)wid * 256 + lane * 4];
  float4 acc;
  acc.x = p0 * bf16_to_f32(hq0.x);
  acc.y = p0 * bf16_to_f32(hq0.y);
  acc.z = p0 * bf16_to_f32(hq0.z);
  acc.w = p0 * bf16_to_f32(hq0.w);

  auto step = [&](float a0, const ushort4& hv) {
    float p = __expf(fminf(leaky(a0 + ad), 80.0f));
    s += p;
    acc.x = fmaf(p, bf16_to_f32(hv.x), acc.x);
    acc.y = fmaf(p, bf16_to_f32(hv.y), acc.y);
    acc.z = fmaf(p, bf16_to_f32(hv.z), acc.z);
    acc.w = fmaf(p, bf16_to_f32(hv.w), acc.w);
  };

  int j0 = offs[wid], j1 = offs[wid + 1];
  int j = j0;
  for (; j + 8 <= j1; j += 8) {
    int si[8];
    float a[8];
    ushort4 hv[8];
#pragma unroll
    for (int u = 0; u < 8; ++u) si[u] = csr[j + u];
#pragma unroll
    for (int u = 0; u < 8; ++u) a[u] = as1[si[u] * 8 + head];
#pragma unroll
    for (int u = 0; u < 8; ++u) hv[u] = *(const ushort4*)&h1b[(size_t)si[u] * 256 + lane * 4];
#pragma unroll
    for (int u = 0; u < 8; ++u) step(a[u], hv[u]);
  }
  for (; j + 4 <= j1; j += 4) {
    int si[4];
    float a[4];
    ushort4 hv[4];
#pragma unroll
    for (int u = 0; u < 4; ++u) si[u] = csr[j + u];
#pragma unroll
    for (int u = 0; u < 4; ++u) a[u] = as1[si[u] * 8 + head];
#pragma unroll
    for (int u = 0; u < 4; ++u) hv[u] = *(const ushort4*)&h1b[(size_t)si[u] * 256 + lane * 4];
#pragma unroll
    for (int u = 0; u < 4; ++u) step(a[u], hv[u]);
  }
  for (; j < j1; ++j) {
    int s0 = csr[j];
    float a0 = as1[s0 * 8 + head];
    ushort4 h0 = *(const ushort4*)&h1b[(size_t)s0 * 256 + lane * 4];
    step(a0, h0);
  }

  float rs = 1.0f / (s + 1e-16f);
  float4 bv = *(const float4*)&b1[lane * 4];
  // non-temporal: don't let the 50MB h2 stream evict h1 gather lines from L2
  nt_store4(&h2[(size_t)wid * 256 + lane * 4],
            fmaxf(fmaf(acc.x, rs, bv.x), 0.0f),
            fmaxf(fmaf(acc.y, rs, bv.y), 0.0f),
            fmaxf(fmaf(acc.z, rs, bv.z), 0.0f),
            fmaxf(fmaf(acc.w, rs, bv.w), 0.0f));
}

// ---------------- alpha for layer 2 (H=1, C=32): wave per node ----------------
__global__ __launch_bounds__(256) void alpha2_kernel(const float* __restrict__ hl2,
                                                     const float* __restrict__ a_src,
                                                     const float* __restrict__ a_dst,
                                                     float* __restrict__ as2,
                                                     float* __restrict__ ad2, int N) {
  int wid = (int)((blockIdx.x * (size_t)blockDim.x + threadIdx.x) >> 6);
  int lane = threadIdx.x & 63;
  if (wid >= N) return;
  int c = lane & 31;
  float w = (lane < 32) ? a_src[c] : a_dst[c];
  float v = hl2[(size_t)wid * 32 + c];
  float p = v * w;
  p += __shfl_xor(p, 1); p += __shfl_xor(p, 2); p += __shfl_xor(p, 4);
  p += __shfl_xor(p, 8); p += __shfl_xor(p, 16);
  if (lane == 0) as2[wid] = p;
  if (lane == 32) ad2[wid] = p;
}

// ---------------- aggregation layer 2: wave per node, C=32 ----------------
__global__ __launch_bounds__(256) void agg2_kernel(const int* __restrict__ offs,
                                                   const int* __restrict__ csr,
                                                   const float* __restrict__ hl2,
                                                   const float* __restrict__ as2,
                                                   const float* __restrict__ ad2,
                                                   const float* __restrict__ b2,
                                                   float* __restrict__ z, int N) {
  int wid = (int)((blockIdx.x * (size_t)blockDim.x + threadIdx.x) >> 6);
  int lane = threadIdx.x & 63;
  if (wid >= N) return;
  int c = lane & 31;

  float ad = ad2[wid];
  float p0 = __expf(fminf(leaky(as2[wid] + ad), 80.0f));
  float s = p0;
  float acc = p0 * hl2[(size_t)wid * 32 + c];

  auto step = [&](float a0, float v0) {
    float p = __expf(fminf(leaky(a0 + ad), 80.0f));
    s += p;
    acc = fmaf(p, v0, acc);
  };

  int j0 = offs[wid], j1 = offs[wid + 1];
  int j = j0;
  for (; j + 8 <= j1; j += 8) {
    int si[8];
    float a[8], v[8];
#pragma unroll
    for (int u = 0; u < 8; ++u) si[u] = csr[j + u];
#pragma unroll
    for (int u = 0; u < 8; ++u) a[u] = as2[si[u]];
#pragma unroll
    for (int u = 0; u < 8; ++u) v[u] = hl2[(size_t)si[u] * 32 + c];
#pragma unroll
    for (int u = 0; u < 8; ++u) step(a[u], v[u]);
  }
  for (; j < j1; ++j) {
    int s0 = csr[j];
    step(as2[s0], hl2[(size_t)s0 * 32 + c]);
  }

  if (lane < 32) {
    float rs = 1.0f / (s + 1e-16f);
    z[(size_t)wid * 32 + c] = fmaf(acc, rs, b2[c]);
  }
}

// ---------------- launch ----------------
extern "C" void kernel_launch(void* const* d_in, const int* in_sizes, int n_in,
                              void* d_out, int out_size, void* d_ws, size_t ws_size,
                              hipStream_t stream) {
  const float* x = (const float*)d_in[0];
  const int* ei = (const int*)d_in[1];  // [2, E]
  const float* W1 = (const float*)d_in[2];
  const float* a_src1 = (const float*)d_in[3];
  const float* a_dst1 = (const float*)d_in[4];
  const float* b1 = (const float*)d_in[5];
  const float* W2 = (const float*)d_in[6];
  const float* a_src2 = (const float*)d_in[7];
  const float* a_dst2 = (const float*)d_in[8];
  const float* b2 = (const float*)d_in[9];
  const float* Wd = (const float*)d_in[10];
  const float* bd = (const float*)d_in[11];
  float* out = (float*)d_out;

  const int IN = 128, HC1 = 256, C2 = 32, OUT = 128;
  int N = in_sizes[0] / IN;
  int E = in_sizes[1] / 2;

  // workspace carve
  char* p = (char*)d_ws;
  auto alloc = [&](size_t bytes) {
    void* r = (void*)p;
    p += (bytes + 255) & ~(size_t)255;
    return r;
  };
  unsigned short* h1b = (unsigned short*)alloc((size_t)N * HC1 * 2);  // bf16 h1
  float* as1 = (float*)alloc((size_t)N * 8 * 4);
  float* ad1 = (float*)alloc((size_t)N * 8 * 4);
  float* h2 = (float*)alloc((size_t)N * HC1 * 4);
  float* hl2 = (float*)alloc((size_t)N * C2 * 4);
  float* as2 = (float*)alloc((size_t)N * 4);
  float* ad2 = (float*)alloc((size_t)N * 4);
  float* z = (float*)alloc((size_t)N * C2 * 4);
  int* counts = (int*)alloc((size_t)N * 4);
  int* cursor = (int*)alloc((size_t)N * 4);
  int* offs = (int*)alloc((size_t)(N + 1) * 4);
  int* csr = (int*)alloc((size_t)E * 4);

  int nblk = (N + 255) / 256;
  int eblk = (E + 255) / 256;
  int wblk = (int)(((size_t)N * 64 + 255) / 256);  // wave-per-node kernels

  // CSR build
  zero_kernel<<<nblk, 256, 0, stream>>>(counts, N);
  count_kernel<<<eblk, 256, 0, stream>>>(ei, counts, E);
  scan_kernel<<<1, 1024, 0, stream>>>(counts, offs, cursor, N);
  fill_kernel<<<eblk, 256, 0, stream>>>(ei, cursor, csr, E);

  // layer 1: h1b = bf16(x @ W1)   (M=N nodes, N=256, K=128)
  {
    dim3 g(HC1 / 128, (N + 127) / 128);
    gemm_big<false, true><<<g, 256, 0, stream>>>(x, W1, nullptr, nullptr, h1b, N, HC1, IN);
  }
  alpha1_kernel<<<wblk, 256, 0, stream>>>(h1b, a_src1, a_dst1, as1, ad1, N);
  agg1_kernel<<<wblk, 256, 0, stream>>>(offs, csr, h1b, as1, ad1, b1, h2, N);

  // layer 2: hl2 = h2 @ W2   (N=32 -> 64x64 kernel with guards)
  {
    dim3 g((N + 63) / 64, 1);
    gemm_tiled<false><<<g, 256, 0, stream>>>(h2, W2, nullptr, hl2, N, C2, HC1);
  }
  alpha2_kernel<<<wblk, 256, 0, stream>>>(hl2, a_src2, a_dst2, as2, ad2, N);
  agg2_kernel<<<wblk, 256, 0, stream>>>(offs, csr, hl2, as2, ad2, b2, z, N);

  // decode: out = z @ Wd + bd   (N=128, K=32)
  {
    dim3 g(OUT / 128, (N + 127) / 128);
    gemm_big<true, false><<<g, 256, 0, stream>>>(z, Wd, bd, out, nullptr, N, OUT, C2);
  }
}

// Round 16
// 402.267 us; speedup vs baseline: 1.4220x; 1.2335x over previous
//
#include <hip/hip_runtime.h>
#include <math.h>

#define NEG_SLOPE 0.2f

typedef float f32x4_t __attribute__((ext_vector_type(4)));

static __device__ __forceinline__ float leaky(float x) {
  return x > 0.0f ? x : NEG_SLOPE * x;
}

static __device__ __forceinline__ void nt_store4(float* p, float a, float b, float c, float d) {
  f32x4_t v = {a, b, c, d};
  __builtin_nontemporal_store(v, (f32x4_t*)p);
}

// bf16 helpers (RNE)
static __device__ __forceinline__ unsigned short f32_to_bf16(float f) {
  unsigned int u = __float_as_uint(f);
  unsigned int r = u + 0x7FFFu + ((u >> 16) & 1u);
  return (unsigned short)(r >> 16);
}
static __device__ __forceinline__ float bf16_to_f32(unsigned short h) {
  return __uint_as_float(((unsigned int)h) << 16);
}

// ---------------- CSR build ----------------
__global__ void zero_kernel(int* __restrict__ p, int n) {
  int i = blockIdx.x * blockDim.x + threadIdx.x;
  if (i < n) p[i] = 0;
}

__global__ void count_kernel(const int* __restrict__ ei, int* __restrict__ counts, int E) {
  int i = blockIdx.x * blockDim.x + threadIdx.x;
  if (i < E) atomicAdd(&counts[ei[E + i]], 1);
}

// ---- parallel 3-pass exclusive scan (replaces 110us single-block scan) ----
// Pass A: block b sums counts[b*1024 .. +1023] -> bsums[b]
__global__ __launch_bounds__(256) void partial_kernel(const int* __restrict__ counts,
                                                      int* __restrict__ bsums, int N) {
  __shared__ int red[256];
  int b = blockIdx.x, tid = threadIdx.x;
  int base = b * 1024;
  int s = 0;
  for (int i = tid; i < 1024; i += 256) {
    int idx = base + i;
    if (idx < N) s += counts[idx];
  }
  red[tid] = s;
  __syncthreads();
  for (int off = 128; off > 0; off >>= 1) {
    if (tid < off) red[tid] += red[tid + off];
    __syncthreads();
  }
  if (tid == 0) bsums[b] = red[0];
}

// Pass B: single block, inclusive Hillis-Steele over nb (<=1024) block sums
// -> boffs (exclusive), offs[N] = total
__global__ __launch_bounds__(1024) void scanb_kernel(const int* __restrict__ bsums,
                                                     int* __restrict__ boffs,
                                                     int* __restrict__ offs, int N, int nb) {
  __shared__ int sh[1024];
  int tid = threadIdx.x;
  sh[tid] = (tid < nb) ? bsums[tid] : 0;
  __syncthreads();
  for (int off = 1; off < 1024; off <<= 1) {
    int v = (tid >= off) ? sh[tid - off] : 0;
    __syncthreads();
    sh[tid] += v;
    __syncthreads();
  }
  if (tid < nb) boffs[tid] = (tid > 0) ? sh[tid - 1] : 0;
  if (tid == 0) offs[N] = sh[1023];
}

// Pass C: block b scans its 1024-element chunk (4/thread), adds boffs[b],
// writes offs + cursor.
__global__ __launch_bounds__(256) void scanc_kernel(const int* __restrict__ counts,
                                                    const int* __restrict__ boffs,
                                                    int* __restrict__ offs,
                                                    int* __restrict__ cursor, int N) {
  __shared__ int sh[256];
  int b = blockIdx.x, tid = threadIdx.x;
  int base = b * 1024 + tid * 4;
  int c0 = 0, c1 = 0, c2 = 0, c3 = 0;
  if (base + 3 < N) {
    int4 v = *(const int4*)&counts[base];
    c0 = v.x; c1 = v.y; c2 = v.z; c3 = v.w;
  } else {
    if (base + 0 < N) c0 = counts[base + 0];
    if (base + 1 < N) c1 = counts[base + 1];
    if (base + 2 < N) c2 = counts[base + 2];
  }
  int tsum = c0 + c1 + c2 + c3;
  sh[tid] = tsum;
  __syncthreads();
  for (int off = 1; off < 256; off <<= 1) {
    int v = (tid >= off) ? sh[tid - off] : 0;
    __syncthreads();
    sh[tid] += v;
    __syncthreads();
  }
  int run = boffs[b] + sh[tid] - tsum;  // exclusive prefix for this thread
  if (base + 0 < N) { offs[base + 0] = run; cursor[base + 0] = run; run += c0; }
  if (base + 1 < N) { offs[base + 1] = run; cursor[base + 1] = run; run += c1; }
  if (base + 2 < N) { offs[base + 2] = run; cursor[base + 2] = run; run += c2; }
  if (base + 3 < N) { offs[base + 3] = run; cursor[base + 3] = run; }
}

__global__ void fill_kernel(const int* __restrict__ ei, int* __restrict__ cursor,
                            int* __restrict__ csr, int E) {
  int i = blockIdx.x * blockDim.x + threadIdx.x;
  if (i < E) {
    int src = ei[i];
    int dst = ei[E + i];
    int pos = atomicAdd(&cursor[dst], 1);
    csr[pos] = src;
  }
}

// ---------------- 64x64-tile f32 GEMM (used for N=32 layer-2 matmul) ----------------
template <bool BIAS>
__global__ __launch_bounds__(256) void gemm_tiled(const float* __restrict__ A,
                                                  const float* __restrict__ B,
                                                  const float* __restrict__ bias,
                                                  float* __restrict__ C,
                                                  int M, int N, int K) {
  __shared__ float As[16][68];  // transposed: As[k][m]
  __shared__ float Bs[16][68];
  int tid = threadIdx.x;
  int tx = tid & 15, ty = tid >> 4;
  int brow = blockIdx.x * 64, bcol = blockIdx.y * 64;

  float acc[4][4] = {};

  int arow = tid >> 2;         // 0..63
  int akv = (tid & 3) * 4;     // 0,4,8,12
  int bkk = tid >> 4;          // 0..15
  int bcv = (tid & 15) * 4;    // 0..60

  for (int k0 = 0; k0 < K; k0 += 16) {
    int gr = min(brow + arow, M - 1);
    float4 av = *(const float4*)&A[(size_t)gr * K + k0 + akv];
    float4 bv;
    int gc = bcol + bcv;
    if (gc + 3 < N)
      bv = *(const float4*)&B[(size_t)(k0 + bkk) * N + gc];
    else
      bv = make_float4(0.f, 0.f, 0.f, 0.f);

    __syncthreads();
    As[akv + 0][arow] = av.x;
    As[akv + 1][arow] = av.y;
    As[akv + 2][arow] = av.z;
    As[akv + 3][arow] = av.w;
    *(float4*)&Bs[bkk][bcv] = bv;
    __syncthreads();

#pragma unroll
    for (int kk = 0; kk < 16; ++kk) {
      float4 a4 = *(const float4*)&As[kk][ty * 4];
      float4 b4 = *(const float4*)&Bs[kk][tx * 4];
      float ar[4] = {a4.x, a4.y, a4.z, a4.w};
      float br[4] = {b4.x, b4.y, b4.z, b4.w};
#pragma unroll
      for (int i = 0; i < 4; ++i)
#pragma unroll
        for (int j = 0; j < 4; ++j) acc[i][j] = fmaf(ar[i], br[j], acc[i][j]);
    }
  }

#pragma unroll
  for (int i = 0; i < 4; ++i) {
    int r = brow + ty * 4 + i;
    if (r >= M) continue;
#pragma unroll
    for (int j = 0; j < 4; ++j) {
      int c = bcol + tx * 4 + j;
      if (c >= N) continue;
      float v = acc[i][j];
      if (BIAS) v += bias[c];
      C[(size_t)r * N + c] = v;
    }
  }
}

// ---------------- 128x128-tile / 8x8-micro f32 GEMM ----------------
// Requires N % 128 == 0, K % 16 == 0. Linear LDS (bijective by construction).
// OUT_BF16: RNE-convert the f32 accumulator and store 16-bit (used for h1).
template <bool BIAS, bool OUT_BF16>
__global__ __launch_bounds__(256) void gemm_big(const float* __restrict__ A,
                                                const float* __restrict__ B,
                                                const float* __restrict__ bias,
                                                float* __restrict__ C,
                                                unsigned short* __restrict__ C16,
                                                int M, int N, int K) {
  __shared__ float As[16][128];  // As[k][m] (transposed)
  __shared__ float Bs[16][128];  // Bs[k][col] (linear)
  int tid = threadIdx.x;
  int tx = tid & 15, ty = tid >> 4;
  int brow = blockIdx.y * 128, bcol = blockIdx.x * 128;

  float acc[8][8] = {};

  int ar = tid >> 1;          // 0..127
  int akv = (tid & 1) * 8;    // 0 or 8
  int bk = tid >> 4;          // 0..15
  int bcv = (tid & 15) * 8;   // 0..120

  const float* Aptr = A + (size_t)min(brow + ar, M - 1) * K + akv;
  const float* Bptr = B + (size_t)bk * N + bcol + bcv;

  for (int k0 = 0; k0 < K; k0 += 16) {
    float4 a0 = *(const float4*)(Aptr + k0);
    float4 a1 = *(const float4*)(Aptr + k0 + 4);
    float4 b0 = *(const float4*)(Bptr + (size_t)k0 * N);
    float4 b1 = *(const float4*)(Bptr + (size_t)k0 * N + 4);

    __syncthreads();
    As[akv + 0][ar] = a0.x;
    As[akv + 1][ar] = a0.y;
    As[akv + 2][ar] = a0.z;
    As[akv + 3][ar] = a0.w;
    As[akv + 4][ar] = a1.x;
    As[akv + 5][ar] = a1.y;
    As[akv + 6][ar] = a1.z;
    As[akv + 7][ar] = a1.w;
    *(float4*)&Bs[bk][bcv] = b0;
    *(float4*)&Bs[bk][bcv + 4] = b1;
    __syncthreads();

#pragma unroll
    for (int kk = 0; kk < 16; ++kk) {
      float4 av0 = *(const float4*)&As[kk][ty * 8];
      float4 av1 = *(const float4*)&As[kk][ty * 8 + 4];
      float4 bv0 = *(const float4*)&Bs[kk][tx * 8];
      float4 bv1 = *(const float4*)&Bs[kk][tx * 8 + 4];
      float ar8[8] = {av0.x, av0.y, av0.z, av0.w, av1.x, av1.y, av1.z, av1.w};
      float br8[8] = {bv0.x, bv0.y, bv0.z, bv0.w, bv1.x, bv1.y, bv1.z, bv1.w};
#pragma unroll
      for (int i = 0; i < 8; ++i)
#pragma unroll
        for (int j = 0; j < 8; ++j) acc[i][j] = fmaf(ar8[i], br8[j], acc[i][j]);
    }
  }

#pragma unroll
  for (int i = 0; i < 8; ++i) {
    int r = brow + ty * 8 + i;
    if (r >= M) continue;
    if (OUT_BF16) {
      int c = bcol + tx * 8;
      ushort4 v0, v1;
      v0.x = f32_to_bf16(acc[i][0]);
      v0.y = f32_to_bf16(acc[i][1]);
      v0.z = f32_to_bf16(acc[i][2]);
      v0.w = f32_to_bf16(acc[i][3]);
      v1.x = f32_to_bf16(acc[i][4]);
      v1.y = f32_to_bf16(acc[i][5]);
      v1.z = f32_to_bf16(acc[i][6]);
      v1.w = f32_to_bf16(acc[i][7]);
      *(ushort4*)&C16[(size_t)r * N + c] = v0;
      *(ushort4*)&C16[(size_t)r * N + c + 4] = v1;
    } else {
#pragma unroll
      for (int j0 = 0; j0 < 8; j0 += 4) {
        int c = bcol + tx * 8 + j0;
        float4 v = {acc[i][j0], acc[i][j0 + 1], acc[i][j0 + 2], acc[i][j0 + 3]};
        if (BIAS) {
          float4 bb = *(const float4*)&bias[c];
          v.x += bb.x; v.y += bb.y; v.z += bb.z; v.w += bb.w;
        }
        *(float4*)&C[(size_t)r * N + c] = v;
      }
    }
  }
}

// ---------------- alpha for layer 1: wave per node, 256-wide bf16 rows ----------------
__global__ __launch_bounds__(256) void alpha1_kernel(const unsigned short* __restrict__ h1b,
                                                     const float* __restrict__ a_src,
                                                     const float* __restrict__ a_dst,
                                                     float* __restrict__ as_out,
                                                     float* __restrict__ ad_out, int N) {
  int wid = (int)((blockIdx.x * (size_t)blockDim.x + threadIdx.x) >> 6);
  int lane = threadIdx.x & 63;
  if (wid >= N) return;
  ushort4 hq = *(const ushort4*)&h1b[(size_t)wid * 256 + lane * 4];
  float4 sv = *(const float4*)&a_src[lane * 4];  // [8,32] flat: h*32+c == lane*4
  float4 dv = *(const float4*)&a_dst[lane * 4];
  float hx = bf16_to_f32(hq.x), hy = bf16_to_f32(hq.y);
  float hz = bf16_to_f32(hq.z), hw = bf16_to_f32(hq.w);
  float ps = hx * sv.x + hy * sv.y + hz * sv.z + hw * sv.w;
  float pd = hx * dv.x + hy * dv.y + hz * dv.z + hw * dv.w;
  ps += __shfl_xor(ps, 1); ps += __shfl_xor(ps, 2); ps += __shfl_xor(ps, 4);
  pd += __shfl_xor(pd, 1); pd += __shfl_xor(pd, 2); pd += __shfl_xor(pd, 4);
  if ((lane & 7) == 0) {
    as_out[wid * 8 + (lane >> 3)] = ps;
    ad_out[wid * 8 + (lane >> 3)] = pd;
  }
}

// ---------------- aggregation layer 1: wave per destination node, bf16 gather ----------
// lane l owns h[head=l>>3][c=(l&7)*4 .. +3]. Softmax without max-subtraction
// (shift-invariant; fminf(e,80) guard). Batch-8: 24 loads in flight per wave.
// h1 is bf16: halves the 800K x 1KB gather stream (the kernel's cost driver).
__global__ __launch_bounds__(256) void agg1_kernel(const int* __restrict__ offs,
                                                   const int* __restrict__ csr,
                                                   const unsigned short* __restrict__ h1b,
                                                   const float* __restrict__ as1,
                                                   const float* __restrict__ ad1,
                                                   const float* __restrict__ b1,
                                                   float* __restrict__ h2, int N) {
  int wid = (int)((blockIdx.x * (size_t)blockDim.x + threadIdx.x) >> 6);
  int lane = threadIdx.x & 63;
  if (wid >= N) return;
  int head = lane >> 3;

  float ad = ad1[wid * 8 + head];
  // self loop (src == dst)
  float p0 = __expf(fminf(leaky(as1[wid * 8 + head] + ad), 80.0f));
  float s = p0;
  ushort4 hq0 = *(const ushort4*)&h1b[(size_t)wid * 256 + lane * 4];
  float4 acc;
  acc.x = p0 * bf16_to_f32(hq0.x);
  acc.y = p0 * bf16_to_f32(hq0.y);
  acc.z = p0 * bf16_to_f32(hq0.z);
  acc.w = p0 * bf16_to_f32(hq0.w);

  auto step = [&](float a0, const ushort4& hv) {
    float p = __expf(fminf(leaky(a0 + ad), 80.0f));
    s += p;
    acc.x = fmaf(p, bf16_to_f32(hv.x), acc.x);
    acc.y = fmaf(p, bf16_to_f32(hv.y), acc.y);
    acc.z = fmaf(p, bf16_to_f32(hv.z), acc.z);
    acc.w = fmaf(p, bf16_to_f32(hv.w), acc.w);
  };

  int j0 = offs[wid], j1 = offs[wid + 1];
  int j = j0;
  for (; j + 8 <= j1; j += 8) {
    int si[8];
    float a[8];
    ushort4 hv[8];
#pragma unroll
    for (int u = 0; u < 8; ++u) si[u] = csr[j + u];
#pragma unroll
    for (int u = 0; u < 8; ++u) a[u] = as1[si[u] * 8 + head];
#pragma unroll
    for (int u = 0; u < 8; ++u) hv[u] = *(const ushort4*)&h1b[(size_t)si[u] * 256 + lane * 4];
#pragma unroll
    for (int u = 0; u < 8; ++u) step(a[u], hv[u]);
  }
  for (; j + 4 <= j1; j += 4) {
    int si[4];
    float a[4];
    ushort4 hv[4];
#pragma unroll
    for (int u = 0; u < 4; ++u) si[u] = csr[j + u];
#pragma unroll
    for (int u = 0; u < 4; ++u) a[u] = as1[si[u] * 8 + head];
#pragma unroll
    for (int u = 0; u < 4; ++u) hv[u] = *(const ushort4*)&h1b[(size_t)si[u] * 256 + lane * 4];
#pragma unroll
    for (int u = 0; u < 4; ++u) step(a[u], hv[u]);
  }
  for (; j < j1; ++j) {
    int s0 = csr[j];
    float a0 = as1[s0 * 8 + head];
    ushort4 h0 = *(const ushort4*)&h1b[(size_t)s0 * 256 + lane * 4];
    step(a0, h0);
  }

  float rs = 1.0f / (s + 1e-16f);
  float4 bv = *(const float4*)&b1[lane * 4];
  // non-temporal: don't let the 50MB h2 stream evict h1 gather lines from L2
  nt_store4(&h2[(size_t)wid * 256 + lane * 4],
            fmaxf(fmaf(acc.x, rs, bv.x), 0.0f),
            fmaxf(fmaf(acc.y, rs, bv.y), 0.0f),
            fmaxf(fmaf(acc.z, rs, bv.z), 0.0f),
            fmaxf(fmaf(acc.w, rs, bv.w), 0.0f));
}

// ---------------- alpha for layer 2 (H=1, C=32): wave per node ----------------
__global__ __launch_bounds__(256) void alpha2_kernel(const float* __restrict__ hl2,
                                                     const float* __restrict__ a_src,
                                                     const float* __restrict__ a_dst,
                                                     float* __restrict__ as2,
                                                     float* __restrict__ ad2, int N) {
  int wid = (int)((blockIdx.x * (size_t)blockDim.x + threadIdx.x) >> 6);
  int lane = threadIdx.x & 63;
  if (wid >= N) return;
  int c = lane & 31;
  float w = (lane < 32) ? a_src[c] : a_dst[c];
  float v = hl2[(size_t)wid * 32 + c];
  float p = v * w;
  p += __shfl_xor(p, 1); p += __shfl_xor(p, 2); p += __shfl_xor(p, 4);
  p += __shfl_xor(p, 8); p += __shfl_xor(p, 16);
  if (lane == 0) as2[wid] = p;
  if (lane == 32) ad2[wid] = p;
}

// ---------------- aggregation layer 2: wave per node, C=32 ----------------
__global__ __launch_bounds__(256) void agg2_kernel(const int* __restrict__ offs,
                                                   const int* __restrict__ csr,
                                                   const float* __restrict__ hl2,
                                                   const float* __restrict__ as2,
                                                   const float* __restrict__ ad2,
                                                   const float* __restrict__ b2,
                                                   float* __restrict__ z, int N) {
  int wid = (int)((blockIdx.x * (size_t)blockDim.x + threadIdx.x) >> 6);
  int lane = threadIdx.x & 63;
  if (wid >= N) return;
  int c = lane & 31;

  float ad = ad2[wid];
  float p0 = __expf(fminf(leaky(as2[wid] + ad), 80.0f));
  float s = p0;
  float acc = p0 * hl2[(size_t)wid * 32 + c];

  auto step = [&](float a0, float v0) {
    float p = __expf(fminf(leaky(a0 + ad), 80.0f));
    s += p;
    acc = fmaf(p, v0, acc);
  };

  int j0 = offs[wid], j1 = offs[wid + 1];
  int j = j0;
  for (; j + 8 <= j1; j += 8) {
    int si[8];
    float a[8], v[8];
#pragma unroll
    for (int u = 0; u < 8; ++u) si[u] = csr[j + u];
#pragma unroll
    for (int u = 0; u < 8; ++u) a[u] = as2[si[u]];
#pragma unroll
    for (int u = 0; u < 8; ++u) v[u] = hl2[(size_t)si[u] * 32 + c];
#pragma unroll
    for (int u = 0; u < 8; ++u) step(a[u], v[u]);
  }
  for (; j < j1; ++j) {
    int s0 = csr[j];
    step(as2[s0], hl2[(size_t)s0 * 32 + c]);
  }

  if (lane < 32) {
    float rs = 1.0f / (s + 1e-16f);
    z[(size_t)wid * 32 + c] = fmaf(acc, rs, b2[c]);
  }
}

// ---------------- launch ----------------
extern "C" void kernel_launch(void* const* d_in, const int* in_sizes, int n_in,
                              void* d_out, int out_size, void* d_ws, size_t ws_size,
                              hipStream_t stream) {
  const float* x = (const float*)d_in[0];
  const int* ei = (const int*)d_in[1];  // [2, E]
  const float* W1 = (const float*)d_in[2];
  const float* a_src1 = (const float*)d_in[3];
  const float* a_dst1 = (const float*)d_in[4];
  const float* b1 = (const float*)d_in[5];
  const float* W2 = (const float*)d_in[6];
  const float* a_src2 = (const float*)d_in[7];
  const float* a_dst2 = (const float*)d_in[8];
  const float* b2 = (const float*)d_in[9];
  const float* Wd = (const float*)d_in[10];
  const float* bd = (const float*)d_in[11];
  float* out = (float*)d_out;

  const int IN = 128, HC1 = 256, C2 = 32, OUT = 128;
  int N = in_sizes[0] / IN;
  int E = in_sizes[1] / 2;

  // workspace carve
  char* p = (char*)d_ws;
  auto alloc = [&](size_t bytes) {
    void* r = (void*)p;
    p += (bytes + 255) & ~(size_t)255;
    return r;
  };
  unsigned short* h1b = (unsigned short*)alloc((size_t)N * HC1 * 2);  // bf16 h1
  float* as1 = (float*)alloc((size_t)N * 8 * 4);
  float* ad1 = (float*)alloc((size_t)N * 8 * 4);
  float* h2 = (float*)alloc((size_t)N * HC1 * 4);
  float* hl2 = (float*)alloc((size_t)N * C2 * 4);
  float* as2 = (float*)alloc((size_t)N * 4);
  float* ad2 = (float*)alloc((size_t)N * 4);
  float* z = (float*)alloc((size_t)N * C2 * 4);
  int* counts = (int*)alloc((size_t)N * 4);
  int* cursor = (int*)alloc((size_t)N * 4);
  int* offs = (int*)alloc((size_t)(N + 1) * 4);
  int* csr = (int*)alloc((size_t)E * 4);
  int nscan = (N + 1023) / 1024;  // scan blocks (49 for N=50000)
  int* bsums = (int*)alloc((size_t)nscan * 4);
  int* boffs = (int*)alloc((size_t)nscan * 4);

  int nblk = (N + 255) / 256;
  int eblk = (E + 255) / 256;
  int wblk = (int)(((size_t)N * 64 + 255) / 256);  // wave-per-node kernels

  // CSR build (parallel 3-pass scan: was a 110us single-block latency chain)
  zero_kernel<<<nblk, 256, 0, stream>>>(counts, N);
  count_kernel<<<eblk, 256, 0, stream>>>(ei, counts, E);
  partial_kernel<<<nscan, 256, 0, stream>>>(counts, bsums, N);
  scanb_kernel<<<1, 1024, 0, stream>>>(bsums, boffs, offs, N, nscan);
  scanc_kernel<<<nscan, 256, 0, stream>>>(counts, boffs, offs, cursor, N);
  fill_kernel<<<eblk, 256, 0, stream>>>(ei, cursor, csr, E);

  // layer 1: h1b = bf16(x @ W1)   (M=N nodes, N=256, K=128)
  {
    dim3 g(HC1 / 128, (N + 127) / 128);
    gemm_big<false, true><<<g, 256, 0, stream>>>(x, W1, nullptr, nullptr, h1b, N, HC1, IN);
  }
  alpha1_kernel<<<wblk, 256, 0, stream>>>(h1b, a_src1, a_dst1, as1, ad1, N);
  agg1_kernel<<<wblk, 256, 0, stream>>>(offs, csr, h1b, as1, ad1, b1, h2, N);

  // layer 2: hl2 = h2 @ W2   (N=32 -> 64x64 kernel with guards)
  {
    dim3 g((N + 63) / 64, 1);
    gemm_tiled<false><<<g, 256, 0, stream>>>(h2, W2, nullptr, hl2, N, C2, HC1);
  }
  alpha2_kernel<<<wblk, 256, 0, stream>>>(hl2, a_src2, a_dst2, as2, ad2, N);
  agg2_kernel<<<wblk, 256, 0, stream>>>(offs, csr, hl2, as2, ad2, b2, z, N);

  // decode: out = z @ Wd + bd   (N=128, K=32)
  {
    dim3 g(OUT / 128, (N + 127) / 128);
    gemm_big<true, false><<<g, 256, 0, stream>>>(z, Wd, bd, out, nullptr, N, OUT, C2);
  }
}